// Round 12
// baseline (1107.927 us; speedup 1.0000x reference)
//
#include <hip/hip_runtime.h>
#include <hip/hip_bf16.h>

#define NVIEW 6
#define NN    6400
#define DD    2048
#define HH    512
#define CC    256
#define EE    204800
#define ZF    768   // C + H

typedef __bf16 bf16x8 __attribute__((ext_vector_type(8)));
typedef __bf16 bf16x4 __attribute__((ext_vector_type(4)));
typedef float  f32x4  __attribute__((ext_vector_type(4)));

__device__ __forceinline__ float b2f(unsigned short u) {
  union { unsigned int i; float f; } c; c.i = ((unsigned int)u) << 16; return c.f;
}

__device__ __forceinline__ void glds16(const void* g, void* l) {
  __builtin_amdgcn_global_load_lds((const __attribute__((address_space(1))) void*)g,
                                   (__attribute__((address_space(3))) void*)l, 16, 0, 0);
}

// ---------------------------------------------------------------------------
// Merged prep: hist | cvt | all weight transposes  (94016 blocks x 256)
// ---------------------------------------------------------------------------
__global__ __launch_bounds__(256) void k_prep(
    const int* __restrict__ dst, int* __restrict__ hist,
    const float* __restrict__ x, __bf16* __restrict__ xb,
    const float* __restrict__ Wb, const float* __restrict__ Wc0,
    __bf16* __restrict__ Wfu,
    const float* __restrict__ Wo, const float* __restrict__ Wf,
    __bf16* __restrict__ WoT, __bf16* __restrict__ WfT,
    const float* __restrict__ Wc1, const float* __restrict__ Wc2,
    __bf16* __restrict__ Wc1T, __bf16* __restrict__ Wc2T)
{
  __shared__ float sh[32][33];
  int id = blockIdx.x;
  if (id < 4800) {                       // ---- hist ----
    int e = (id % 800) * 256 + threadIdx.x;
    int v = id / 800;
    if (e < EE) atomicAdd(&hist[v * NN + dst[(size_t)v * EE + e]], 1);
    return;
  }
  id -= 4800;
  if (id < 76800) {                      // ---- cvt ----
    size_t i = (size_t)id * 256 + threadIdx.x;
    float4 q = ((const float4*)x)[i];
    bf16x4 o;
    o[0] = (__bf16)q.x; o[1] = (__bf16)q.y; o[2] = (__bf16)q.z; o[3] = (__bf16)q.w;
    *(bf16x4*)(xb + i * 4) = o;
    return;
  }
  id -= 76800;
  // ---- transpose segments ----
  const float* I; __bf16* O; int K, N, bx, by;
  if (id < 6144) {                       // Wb
    bx = id & 63; int r = id >> 6; by = r & 15; int b = r >> 4;
    I = Wb + (size_t)b * DD * HH;
    O = Wfu + (size_t)b * ZF * DD;
    K = DD; N = HH;
  } else if (id < 6144 + 3072) {         // Wc0 (shared input, per-view output)
    id -= 6144;
    bx = id & 63; int r = id >> 6; by = r & 7; int b = r >> 3;
    I = Wc0;
    O = Wfu + (size_t)HH * DD + (size_t)b * ZF * DD;
    K = DD; N = CC;
  } else if (id < 6144 + 3072 + 3072) {  // Wo / Wf
    id -= 6144 + 3072;
    bx = id & 15; int r = id >> 4; by = r & 15; int z = r >> 4;
    if (z < 6) { I = Wo + (size_t)z * HH * HH; O = WoT + (size_t)z * HH * HH; }
    else       { I = Wf + (size_t)(z - 6) * HH * HH; O = WfT + (size_t)(z - 6) * HH * HH; }
    K = HH; N = HH;
  } else {                               // Wc1 / Wc2
    id -= 6144 + 3072 + 3072;
    bx = id & 7; int r = id >> 3; by = r & 7; int z = r >> 3;
    I = (z == 0) ? Wc1 : Wc2;
    O = (z == 0) ? Wc1T : Wc2T;
    K = CC; N = CC;
  }
  int k0 = bx * 32, n0 = by * 32;
  int tx = threadIdx.x & 31, ty = threadIdx.x >> 5;
#pragma unroll
  for (int r = 0; r < 4; r++)
    sh[ty + r * 8][tx] = I[(size_t)(k0 + ty + r * 8) * N + n0 + tx];
  __syncthreads();
#pragma unroll
  for (int r = 0; r < 4; r++)
    O[(size_t)(n0 + ty + r * 8) * K + k0 + tx] = (__bf16)sh[tx][ty + r * 8];
}

// ---------------------------------------------------------------------------
// scan + cursor write fused (cursor aliases hist; hist reads complete before)
// ---------------------------------------------------------------------------
__global__ __launch_bounds__(1024) void k_scan(const int* __restrict__ hist,
                                               int* __restrict__ rp,
                                               int* __restrict__ cur) {
  int v = blockIdx.x;
  const int* h = hist + v * NN;
  int* r = rp + v * (NN + 1);
  __shared__ int part[1024];
  int t = threadIdx.x;
  const int CH = 7;
  int base = t * CH;
  int loc[CH];
  int s = 0;
#pragma unroll
  for (int i = 0; i < CH; i++) {
    int idx = base + i;
    int val = (idx < NN) ? h[idx] : 0;
    loc[i] = s;
    s += val;
  }
  part[t] = s;
  __syncthreads();
  for (int off = 1; off < 1024; off <<= 1) {
    int x = (t >= off) ? part[t - off] : 0;
    __syncthreads();
    part[t] += x;
    __syncthreads();
  }
  int pre = (t == 0) ? 0 : part[t - 1];
#pragma unroll
  for (int i = 0; i < CH; i++) {
    int idx = base + i;
    if (idx < NN) {
      int val = pre + loc[i];
      r[idx] = val;
      cur[v * NN + idx] = val;
    }
  }
  if (t == 1023) r[NN] = part[1023];
}

__global__ void k_scatter(const int* __restrict__ src, const int* __restrict__ dstA,
                          const float* __restrict__ val, int* __restrict__ cur,
                          int2* __restrict__ sedge) {
  int e = blockIdx.x * 256 + threadIdx.x;
  int v = blockIdx.y;
  if (e < EE) {
    size_t idx = (size_t)v * EE + e;
    int d = dstA[idx];
    int pos = atomicAdd(&cur[v * NN + d], 1);
    sedge[(size_t)v * EE + pos] = make_int2(src[idx], __float_as_int(val[idx]));
  }
}

// ---------------------------------------------------------------------------
// 8-phase pipelined bf16 MFMA GEMM body (R8 verified, coalesced staging map).
// ---------------------------------------------------------------------------
__device__ __forceinline__ void g256_body(
    const __bf16* __restrict__ A, const __bf16* __restrict__ BT,
    __bf16* __restrict__ C, int K, int Nc, int nbn, int bpv, int wPerView,
    int orig, int nwg, __bf16* ldsv)
{
  int tid = threadIdx.x, lane = tid & 63, w = tid >> 6;

  int q8 = nwg >> 3, r8 = nwg & 7;
  int xcd = orig & 7, j = orig >> 3;
  int swz = (xcd < r8 ? xcd * (q8 + 1) : r8 * (q8 + 1) + (xcd - r8) * q8) + j;
  int v = swz / bpv; int rr = swz - v * bpv;
  int bm = rr / nbn; int bn = rr - bm * nbn;

  const __bf16* Av = A + (size_t)v * NN * K + (size_t)(bm * 256) * K;
  const __bf16* Bv = BT + (wPerView ? (size_t)v * Nc * K : 0) + (size_t)(bn * 256) * K;

  f32x4 acc[8][4];
#pragma unroll
  for (int m = 0; m < 8; m++)
#pragma unroll
    for (int n = 0; n < 4; n++) acc[m][n] = (f32x4){0.f, 0.f, 0.f, 0.f};

  const int wr = (w >> 2) * 128, wc = (w & 3) * 64;
  const int gq = lane >> 4, l15 = lane & 15;

#define STAGE_UNIT(Gp, LOFF, KH, KT)                                          \
  {                                                                           \
    _Pragma("unroll")                                                         \
    for (int g2 = 0; g2 < 2; g2++) {                                          \
      int u = g2 * 512 + tid;                                                 \
      int row_ = ((u >> 5) << 3) | (u & 7);                                   \
      int kkgl_ = (u >> 3) & 3;                                               \
      glds16(Gp + (size_t)row_ * K + (KT) * 64 + (KH) * 32 + kkgl_ * 8,       \
             ldsv + (LOFF) + (KH) * 8192 + u * 8);                            \
    }                                                                         \
  }

#define PH_READS(KK, MH, LOADB)                                               \
  {                                                                           \
    _Pragma("unroll")                                                         \
    for (int m = 0; m < 4; m++) {                                             \
      int ra = wr + (MH) * 64 + m * 16 + l15;                                 \
      aF[m] = *(const bf16x8*)&Ab[(KK) * 8192 + (ra >> 3) * 256 + gq * 64 +   \
                                  (ra & 7) * 8];                              \
    }                                                                         \
    if (LOADB) {                                                              \
      _Pragma("unroll")                                                       \
      for (int n = 0; n < 4; n++) {                                           \
        int rb = wc + n * 16 + l15;                                           \
        bF[n] = *(const bf16x8*)&Bb[(KK) * 8192 + (rb >> 3) * 256 + gq * 64 + \
                                    (rb & 7) * 8];                            \
      }                                                                       \
    }                                                                         \
  }

#define PH_MFMA(MH)                                                           \
  {                                                                           \
    __builtin_amdgcn_s_barrier();                                             \
    asm volatile("s_waitcnt lgkmcnt(0)" ::: "memory");                        \
    __builtin_amdgcn_sched_barrier(0);                                        \
    __builtin_amdgcn_s_setprio(1);                                            \
    _Pragma("unroll")                                                         \
    for (int m = 0; m < 4; m++)                                               \
      _Pragma("unroll")                                                       \
      for (int n = 0; n < 4; n++)                                             \
        acc[(MH) * 4 + m][n] = __builtin_amdgcn_mfma_f32_16x16x32_bf16(       \
            aF[m], bF[n], acc[(MH) * 4 + m][n], 0, 0, 0);                     \
    __builtin_amdgcn_s_setprio(0);                                            \
    __builtin_amdgcn_s_barrier();                                             \
  }

  const int nt = K >> 6;
  const int ni = nt >> 1;

  STAGE_UNIT(Av, 0,     0, 0);
  STAGE_UNIT(Bv, 16384, 0, 0);
  STAGE_UNIT(Av, 0,     1, 0);
  STAGE_UNIT(Bv, 16384, 1, 0);
  STAGE_UNIT(Av, 32768, 0, 1);
  STAGE_UNIT(Bv, 49152, 0, 1);
  asm volatile("s_waitcnt vmcnt(4)" ::: "memory");
  __builtin_amdgcn_s_barrier();

  bf16x8 aF[4], bF[4];
  for (int i = 0; i < ni; ++i) {
    int t1 = 2 * i + 1, t2 = 2 * i + 2, t3 = 2 * i + 3;
    bool more = (i + 1 < ni);
    const __bf16* Ab = ldsv;
    const __bf16* Bb = ldsv + 16384;
    PH_READS(0, 0, true);
    STAGE_UNIT(Av, 32768, 1, t1);
    asm volatile("s_waitcnt vmcnt(6)" ::: "memory");
    PH_MFMA(0);
    PH_READS(0, 1, false); STAGE_UNIT(Bv, 49152, 1, t1);              PH_MFMA(1);
    PH_READS(1, 0, true);
    if (more) {
      STAGE_UNIT(Av, 0, 0, t2);
      asm volatile("s_waitcnt vmcnt(6)" ::: "memory");
    } else {
      asm volatile("s_waitcnt vmcnt(4)" ::: "memory");
    }
    PH_MFMA(0);
    PH_READS(1, 1, false); if (more) STAGE_UNIT(Bv, 16384, 0, t2);    PH_MFMA(1);
    Ab = ldsv + 32768; Bb = ldsv + 49152;
    PH_READS(0, 0, true);
    if (more) {
      STAGE_UNIT(Av, 0, 1, t2);
      asm volatile("s_waitcnt vmcnt(6)" ::: "memory");
    } else {
      asm volatile("s_waitcnt vmcnt(0)" ::: "memory");
    }
    PH_MFMA(0);
    PH_READS(0, 1, false); if (more) STAGE_UNIT(Bv, 16384, 1, t2);    PH_MFMA(1);
    PH_READS(1, 0, true);
    if (more) {
      STAGE_UNIT(Av, 32768, 0, t3);
      asm volatile("s_waitcnt vmcnt(6)" ::: "memory");
    }
    PH_MFMA(0);
    PH_READS(1, 1, false);
    if (more) STAGE_UNIT(Bv, 49152, 0, t3);
    PH_MFMA(1);
  }

#undef STAGE_UNIT
#undef PH_READS
#undef PH_MFMA

  __bf16* Cv = C + (size_t)v * NN * Nc;
#pragma unroll
  for (int m = 0; m < 8; m++) {
    int rbase = bm * 256 + wr + m * 16 + (lane >> 4) * 4;
#pragma unroll
    for (int q = 0; q < 4; q++) {
      __bf16* cp = Cv + (size_t)(rbase + q) * Nc + bn * 256 + wc + l15;
#pragma unroll
      for (int n = 0; n < 4; n++) cp[n * 16] = (__bf16)acc[m][n][q];
    }
  }
}

__global__ __launch_bounds__(512, 2) void k_g256s(
    const __bf16* __restrict__ A, const __bf16* __restrict__ BT,
    __bf16* __restrict__ C, int K, int Nc, int nbn, int bpv, int wPerView)
{
  __shared__ __bf16 ldsv[65536];
  g256_body(A, BT, C, K, Nc, nbn, bpv, wPerView, blockIdx.x, gridDim.x, ldsv);
}

// paired GEMM launch: blocks [0,S1) = set 1, [S1,grid) = set 2
__global__ __launch_bounds__(512, 2) void k_g256p(
    const __bf16* A1, const __bf16* B1, __bf16* C1,
    int K1, int Nc1, int nbn1, int bpv1, int w1, int S1,
    const __bf16* A2, const __bf16* B2, __bf16* C2,
    int K2, int Nc2, int nbn2, int bpv2, int w2)
{
  __shared__ __bf16 ldsv[65536];
  if ((int)blockIdx.x < S1)
    g256_body(A1, B1, C1, K1, Nc1, nbn1, bpv1, w1, blockIdx.x, S1, ldsv);
  else
    g256_body(A2, B2, C2, K2, Nc2, nbn2, bpv2, w2, blockIdx.x - S1,
              gridDim.x - S1, ldsv);
}

// ---------------------------------------------------------------------------
// CSR SpMM v3: 8 rows/block (512 thr), int32 gather offsets (tables <59MB ->
// SGPR base + 32-bit voffset, no 64-bit VALU adds), explicit dword bf16
// unpack (1 VALU/element). Memory pattern & reduction order = R8 verified.
// ---------------------------------------------------------------------------
template <int LDIN, int FOFF, int F, int CHUNKS, int MODE>
__device__ __forceinline__ void spmm_body(
    int id, const __bf16* __restrict__ in, const int* __restrict__ rp,
    const int2* __restrict__ sedge, void* __restrict__ out,
    const __bf16* __restrict__ h1, const __bf16* __restrict__ h2)
{
  int s = id & 7, j = id >> 3;
  int ch, v, rowblk;
  if (CHUNKS == 2) {                 // XCDs 0-3 -> chunk0, 4-7 -> chunk1
    ch = s >> 2; int q = s & 3;
    v = j / 200; int t = j - v * 200;
    rowblk = t * 4 + q;              // [0,800)
  } else {
    ch = 0;
    v = j / 100; int t = j - v * 100;
    rowblk = t * 8 + s;              // [0,800)
  }
  int wid = threadIdx.x >> 6, lane = threadIdx.x & 63;
  int n = rowblk * 8 + wid;
  int f0 = ch * 256 + lane * 4;

  const int* rpv = rp + v * (NN + 1);
  int e = rpv[n], end = rpv[n + 1];
  const int2* ev = sedge + (size_t)v * EE;
  const __bf16* inv = in + (size_t)v * NN * LDIN + FOFF;   // wave-uniform base

  float a0 = 0.f, a1 = 0.f, a2 = 0.f, a3 = 0.f;

#define GACC(EP)                                                              \
  {                                                                           \
    float wv = __int_as_float((EP).y);                                        \
    int off = (EP).x * LDIN + f0;                                             \
    uint2 rdw = *(const uint2*)(inv + off);                                   \
    a0 += wv * __uint_as_float(rdw.x << 16);                                  \
    a1 += wv * __uint_as_float(rdw.x & 0xffff0000u);                          \
    a2 += wv * __uint_as_float(rdw.y << 16);                                  \
    a3 += wv * __uint_as_float(rdw.y & 0xffff0000u);                          \
  }

  for (; e + 8 <= end; e += 8) {
    int2 ee[8];
#pragma unroll
    for (int u = 0; u < 8; u++) ee[u] = ev[e + u];
#pragma unroll
    for (int u = 0; u < 8; u++) GACC(ee[u]);
  }
  if (e + 4 <= end) {
    int2 ee[4];
#pragma unroll
    for (int u = 0; u < 4; u++) ee[u] = ev[e + u];
#pragma unroll
    for (int u = 0; u < 4; u++) GACC(ee[u]);
    e += 4;
  }
  for (; e < end; ++e) {
    int2 e0 = ev[e];
    GACC(e0);
  }
#undef GACC

  if (MODE == 0) {
    __bf16* o = (__bf16*)out + ((size_t)v * NN + n) * F + f0;
    bf16x4 ov;
    ov[0] = (__bf16)fmaxf(a0, 0.f); ov[1] = (__bf16)fmaxf(a1, 0.f);
    ov[2] = (__bf16)fmaxf(a2, 0.f); ov[3] = (__bf16)fmaxf(a3, 0.f);
    *(bf16x4*)o = ov;
  } else if (MODE == 1) {
    float* o = (float*)out + ((size_t)v * NN + n) * ZF + f0;
    o[0] = fmaxf(a0, 0.f); o[1] = fmaxf(a1, 0.f);
    o[2] = fmaxf(a2, 0.f); o[3] = fmaxf(a3, 0.f);
  } else {
    const __bf16* hh = h1 + ((size_t)v * NN + n) * 512 + f0;
    const __bf16* mm = h2 + ((size_t)v * NN + n) * 512 + f0;
    ushort4 hu = *(const ushort4*)hh;
    ushort4 mu = *(const ushort4*)mm;
    float* o = (float*)out + ((size_t)v * NN + n) * ZF + CC + f0;
    o[0] = (b2f(hu.x) + b2f(mu.x) + a0) * (1.f / 3.f);
    o[1] = (b2f(hu.y) + b2f(mu.y) + a1) * (1.f / 3.f);
    o[2] = (b2f(hu.z) + b2f(mu.z) + a2) * (1.f / 3.f);
    o[3] = (b2f(hu.w) + b2f(mu.w) + a3) * (1.f / 3.f);
  }
}

// paired spmm launch: [0,S1) = variant 1, [S1,grid) = variant 2.
// S1 = 9600 is 0 mod 8 -> XCD phase of segment 2 preserved.
template <int S1,
          int LD1, int FO1, int F1, int CH1, int MO1,
          int LD2, int FO2, int F2, int CH2, int MO2>
__global__ __launch_bounds__(512) void k_spmm2(
    const __bf16* __restrict__ in1, void* __restrict__ out1,
    const __bf16* __restrict__ in2, void* __restrict__ out2,
    const int* __restrict__ rp, const int2* __restrict__ sedge,
    const __bf16* __restrict__ h1, const __bf16* __restrict__ h2)
{
  int id = blockIdx.x;
  if (id < S1) spmm_body<LD1, FO1, F1, CH1, MO1>(id, in1, rp, sedge, out1, h1, h2);
  else         spmm_body<LD2, FO2, F2, CH2, MO2>(id - S1, in2, rp, sedge, out2, h1, h2);
}

// ---------------------------------------------------------------------------
// Gate
// ---------------------------------------------------------------------------
__global__ __launch_bounds__(256) void k_gate(
    const float* __restrict__ Z, const float* __restrict__ gw,
    const float* __restrict__ gb, float* __restrict__ zg)
{
  __shared__ float Zl[NVIEW * ZF];
  __shared__ float sred[36];
  __shared__ float pl[36];
  int n = blockIdx.x, tid = threadIdx.x;

  for (int idx = tid; idx < NVIEW * ZF; idx += 256) {
    int i = idx / ZF, f = idx - i * ZF;
    Zl[idx] = Z[((size_t)i * NN + n) * ZF + f];
  }
  if (tid < 36) sred[tid] = 0.f;
  __syncthreads();

  float acc[36];
#pragma unroll
  for (int p = 0; p < 36; p++) acc[p] = 0.f;
#pragma unroll
  for (int q = 0; q < 3; q++) {
    int f = tid + q * 256;
    float zv[NVIEW];
#pragma unroll
    for (int i = 0; i < NVIEW; i++) zv[i] = Zl[i * ZF + f];
#pragma unroll
    for (int k = 0; k < NVIEW; k++)
#pragma unroll
      for (int i = 0; i < NVIEW; i++)
        acc[k * 6 + i] += zv[i] * gw[(k * 6 + i) * ZF + f];
  }
  int lane = tid & 63;
#pragma unroll
  for (int p = 0; p < 36; p++) {
    float x = acc[p];
    x += __shfl_down(x, 32, 64);
    x += __shfl_down(x, 16, 64);
    x += __shfl_down(x, 8, 64);
    x += __shfl_down(x, 4, 64);
    x += __shfl_down(x, 2, 64);
    x += __shfl_down(x, 1, 64);
    if (lane == 0) atomicAdd(&sred[p], x);
  }
  __syncthreads();

  if (tid < NVIEW) {
    int k = tid;
    float sc[NVIEW];
    float mx = -1e30f;
#pragma unroll
    for (int i = 0; i < NVIEW; i++) {
      sc[i] = sred[k * 6 + i] + gb[k * 6 + i];
      mx = fmaxf(mx, sc[i]);
    }
    float sum = 0.f;
#pragma unroll
    for (int i = 0; i < NVIEW; i++) { sc[i] = __expf(sc[i] - mx); sum += sc[i]; }
    float inv = 1.f / sum;
#pragma unroll
    for (int i = 0; i < NVIEW; i++) pl[k * 6 + i] = sc[i] * inv;
  }
  __syncthreads();

#pragma unroll
  for (int q = 0; q < 3; q++) {
    int f = tid + q * 256;
    float zv[NVIEW];
#pragma unroll
    for (int i = 0; i < NVIEW; i++) zv[i] = Zl[i * ZF + f];
#pragma unroll
    for (int k = 0; k < NVIEW; k++) {
      float o = 0.f;
#pragma unroll
      for (int i = 0; i < NVIEW; i++) o += pl[k * 6 + i] * zv[i];
      zg[((size_t)k * NN + n) * ZF + f] = o;
    }
  }
}

// ---------------------------------------------------------------------------
extern "C" void kernel_launch(void* const* d_in, const int* in_sizes, int n_in,
                              void* d_out, int out_size, void* d_ws, size_t ws_size,
                              hipStream_t stream) {
  const float* x    = (const float*)d_in[0];
  const float* aval = (const float*)d_in[1];
  const float* Wb   = (const float*)d_in[2];
  const float* Wo   = (const float*)d_in[3];
  const float* Wf   = (const float*)d_in[4];
  const float* Wc0  = (const float*)d_in[5];
  const float* Wc1  = (const float*)d_in[6];
  const float* Wc2  = (const float*)d_in[7];
  const float* gw   = (const float*)d_in[8];
  const float* gb   = (const float*)d_in[9];
  const int*   asrc = (const int*)d_in[10];
  const int*   adst = (const int*)d_in[11];

  float* zg = (float*)d_out;                       // [6][6400][768]
  float* Z  = zg + (size_t)NVIEW * NN * ZF;        // [6][6400][768]
  // xb (79 MB bf16 copy of x) is stashed at the head of d_out: its last read
  // (the fused GEMM) precedes the first write to Z (spmm modes 1/2) in stream
  // order; zg is written only by the final gate kernel.
  __bf16* xb = (__bf16*)d_out;

  char* w = (char*)d_ws;
  auto alloc = [&](size_t bytes) {
    char* p = w;
    w += (bytes + 255) & ~(size_t)255;
    return p;
  };
  int*    hist  = (int*)alloc((size_t)NVIEW * NN * 4);          // reused as cursor
  int*    rp    = (int*)alloc((size_t)NVIEW * (NN + 1) * 4);
  int2*   sedge = (int2*)alloc((size_t)NVIEW * EE * 8);
  __bf16* Wfu   = (__bf16*)alloc((size_t)NVIEW * ZF * DD * 2);  // [v][768][2048]
  __bf16* WoT   = (__bf16*)alloc((size_t)NVIEW * HH * HH * 2);
  __bf16* WfT   = (__bf16*)alloc((size_t)NVIEW * HH * HH * 2);
  __bf16* Wc1T  = (__bf16*)alloc((size_t)CC * CC * 2);
  __bf16* Wc2T  = (__bf16*)alloc((size_t)CC * CC * 2);
  __bf16* tf768 = (__bf16*)alloc((size_t)NVIEW * NN * ZF * 2);  // fused GEMM out
  __bf16* t512b = (__bf16*)alloc((size_t)NVIEW * NN * HH * 2);
  __bf16* hidb  = (__bf16*)alloc((size_t)NVIEW * NN * HH * 2);
  __bf16* midb  = (__bf16*)alloc((size_t)NVIEW * NN * HH * 2);
  __bf16* tcb   = (__bf16*)alloc((size_t)NVIEW * NN * CC * 2);
  __bf16* cbb   = (__bf16*)alloc((size_t)NVIEW * NN * CC * 2);

  // ---- CSR build + precision/layout prep (merged) ----
  (void)hipMemsetAsync(hist, 0, (size_t)NVIEW * NN * 4, stream);
  k_prep<<<94016, 256, 0, stream>>>(adst, hist, x, xb, Wb, Wc0, Wfu,
                                    Wo, Wf, WoT, WfT, Wc1, Wc2, Wc1T, Wc2T);
  k_scan<<<NVIEW, 1024, 0, stream>>>(hist, rp, hist);   // cursor fused (alias)
  k_scatter<<<dim3(800, NVIEW), 256, 0, stream>>>(asrc, adst, aval, hist, sedge);

  // ---- fused first-layer GEMM: [6400,2048] @ [2048,768] per view ----
  k_g256s<<<450, 512, 0, stream>>>(xb, Wfu, tf768, DD, ZF, 3, 75, 1);

  // ---- layer pipeline: view path (512f) + common path (256f), paired ----
  k_spmm2<9600, 768, 0, 512, 2, 0, 768, 512, 256, 1, 0>
      <<<14400, 512, 0, stream>>>(tf768, hidb, tf768, cbb, rp, sedge, nullptr, nullptr);
  k_g256p<<<450, 512, 0, stream>>>(hidb, WoT, t512b, HH, HH, 2, 50, 1, 300,
                                   cbb, Wc1T, tcb, CC, CC, 1, 25, 0);
  k_spmm2<9600, 512, 0, 512, 2, 0, 256, 0, 256, 1, 0>
      <<<14400, 512, 0, stream>>>(t512b, midb, tcb, cbb, rp, sedge, nullptr, nullptr);
  k_g256p<<<450, 512, 0, stream>>>(midb, WfT, t512b, HH, HH, 2, 50, 1, 300,
                                   cbb, Wc2T, tcb, CC, CC, 1, 25, 0);
  k_spmm2<9600, 512, 0, 512, 2, 2, 256, 0, 256, 1, 1>
      <<<14400, 512, 0, stream>>>(t512b, Z, tcb, Z, rp, sedge, hidb, midb);

  // ---- gated fusion ----
  k_gate<<<NN, 256, 0, stream>>>(Z, gw, gb, zg);
}

// Round 13
// 1098.339 us; speedup vs baseline: 1.0087x; 1.0087x over previous
//
#include <hip/hip_runtime.h>
#include <hip/hip_bf16.h>

#define NVIEW 6
#define NN    6400
#define DD    2048
#define HH    512
#define CC    256
#define EE    204800
#define ZF    768   // C + H

typedef __bf16 bf16x8 __attribute__((ext_vector_type(8)));
typedef __bf16 bf16x4 __attribute__((ext_vector_type(4)));
typedef float  f32x4  __attribute__((ext_vector_type(4)));

__device__ __forceinline__ float b2f(unsigned short u) {
  union { unsigned int i; float f; } c; c.i = ((unsigned int)u) << 16; return c.f;
}

__device__ __forceinline__ void glds16(const void* g, void* l) {
  __builtin_amdgcn_global_load_lds((const __attribute__((address_space(1))) void*)g,
                                   (__attribute__((address_space(3))) void*)l, 16, 0, 0);
}

// ---------------------------------------------------------------------------
// Merged prep: hist | cvt | all weight transposes  (94016 blocks x 256)
// ---------------------------------------------------------------------------
__global__ __launch_bounds__(256) void k_prep(
    const int* __restrict__ dst, int* __restrict__ hist,
    const float* __restrict__ x, __bf16* __restrict__ xb,
    const float* __restrict__ Wb, const float* __restrict__ Wc0,
    __bf16* __restrict__ Wfu,
    const float* __restrict__ Wo, const float* __restrict__ Wf,
    __bf16* __restrict__ WoT, __bf16* __restrict__ WfT,
    const float* __restrict__ Wc1, const float* __restrict__ Wc2,
    __bf16* __restrict__ Wc1T, __bf16* __restrict__ Wc2T)
{
  __shared__ float sh[32][33];
  int id = blockIdx.x;
  if (id < 4800) {                       // ---- hist ----
    int e = (id % 800) * 256 + threadIdx.x;
    int v = id / 800;
    if (e < EE) atomicAdd(&hist[v * NN + dst[(size_t)v * EE + e]], 1);
    return;
  }
  id -= 4800;
  if (id < 76800) {                      // ---- cvt ----
    size_t i = (size_t)id * 256 + threadIdx.x;
    float4 q = ((const float4*)x)[i];
    bf16x4 o;
    o[0] = (__bf16)q.x; o[1] = (__bf16)q.y; o[2] = (__bf16)q.z; o[3] = (__bf16)q.w;
    *(bf16x4*)(xb + i * 4) = o;
    return;
  }
  id -= 76800;
  // ---- transpose segments ----
  const float* I; __bf16* O; int K, N, bx, by;
  if (id < 6144) {                       // Wb
    bx = id & 63; int r = id >> 6; by = r & 15; int b = r >> 4;
    I = Wb + (size_t)b * DD * HH;
    O = Wfu + (size_t)b * ZF * DD;
    K = DD; N = HH;
  } else if (id < 6144 + 3072) {         // Wc0 (shared input, per-view output)
    id -= 6144;
    bx = id & 63; int r = id >> 6; by = r & 7; int b = r >> 3;
    I = Wc0;
    O = Wfu + (size_t)HH * DD + (size_t)b * ZF * DD;
    K = DD; N = CC;
  } else if (id < 6144 + 3072 + 3072) {  // Wo / Wf
    id -= 6144 + 3072;
    bx = id & 15; int r = id >> 4; by = r & 15; int z = r >> 4;
    if (z < 6) { I = Wo + (size_t)z * HH * HH; O = WoT + (size_t)z * HH * HH; }
    else       { I = Wf + (size_t)(z - 6) * HH * HH; O = WfT + (size_t)(z - 6) * HH * HH; }
    K = HH; N = HH;
  } else {                               // Wc1 / Wc2
    id -= 6144 + 3072 + 3072;
    bx = id & 7; int r = id >> 3; by = r & 7; int z = r >> 3;
    I = (z == 0) ? Wc1 : Wc2;
    O = (z == 0) ? Wc1T : Wc2T;
    K = CC; N = CC;
  }
  int k0 = bx * 32, n0 = by * 32;
  int tx = threadIdx.x & 31, ty = threadIdx.x >> 5;
#pragma unroll
  for (int r = 0; r < 4; r++)
    sh[ty + r * 8][tx] = I[(size_t)(k0 + ty + r * 8) * N + n0 + tx];
  __syncthreads();
#pragma unroll
  for (int r = 0; r < 4; r++)
    O[(size_t)(n0 + ty + r * 8) * K + k0 + tx] = (__bf16)sh[tx][ty + r * 8];
}

// ---------------------------------------------------------------------------
// scan + cursor write fused (cursor aliases hist; hist reads complete before)
// ---------------------------------------------------------------------------
__global__ __launch_bounds__(1024) void k_scan(const int* __restrict__ hist,
                                               int* __restrict__ rp,
                                               int* __restrict__ cur) {
  int v = blockIdx.x;
  const int* h = hist + v * NN;
  int* r = rp + v * (NN + 1);
  __shared__ int part[1024];
  int t = threadIdx.x;
  const int CH = 7;
  int base = t * CH;
  int loc[CH];
  int s = 0;
#pragma unroll
  for (int i = 0; i < CH; i++) {
    int idx = base + i;
    int val = (idx < NN) ? h[idx] : 0;
    loc[i] = s;
    s += val;
  }
  part[t] = s;
  __syncthreads();
  for (int off = 1; off < 1024; off <<= 1) {
    int x = (t >= off) ? part[t - off] : 0;
    __syncthreads();
    part[t] += x;
    __syncthreads();
  }
  int pre = (t == 0) ? 0 : part[t - 1];
#pragma unroll
  for (int i = 0; i < CH; i++) {
    int idx = base + i;
    if (idx < NN) {
      int val = pre + loc[i];
      r[idx] = val;
      cur[v * NN + idx] = val;
    }
  }
  if (t == 1023) r[NN] = part[1023];
}

__global__ void k_scatter(const int* __restrict__ src, const int* __restrict__ dstA,
                          const float* __restrict__ val, int* __restrict__ cur,
                          int2* __restrict__ sedge) {
  int e = blockIdx.x * 256 + threadIdx.x;
  int v = blockIdx.y;
  if (e < EE) {
    size_t idx = (size_t)v * EE + e;
    int d = dstA[idx];
    int pos = atomicAdd(&cur[v * NN + d], 1);
    sedge[(size_t)v * EE + pos] = make_int2(src[idx], __float_as_int(val[idx]));
  }
}

// ---------------------------------------------------------------------------
// 8-phase pipelined bf16 MFMA GEMM body (R8 verified, coalesced staging map).
// ---------------------------------------------------------------------------
__device__ __forceinline__ void g256_body(
    const __bf16* __restrict__ A, const __bf16* __restrict__ BT,
    __bf16* __restrict__ C, int K, int Nc, int nbn, int bpv, int wPerView,
    int orig, int nwg, __bf16* ldsv)
{
  int tid = threadIdx.x, lane = tid & 63, w = tid >> 6;

  int q8 = nwg >> 3, r8 = nwg & 7;
  int xcd = orig & 7, j = orig >> 3;
  int swz = (xcd < r8 ? xcd * (q8 + 1) : r8 * (q8 + 1) + (xcd - r8) * q8) + j;
  int v = swz / bpv; int rr = swz - v * bpv;
  int bm = rr / nbn; int bn = rr - bm * nbn;

  const __bf16* Av = A + (size_t)v * NN * K + (size_t)(bm * 256) * K;
  const __bf16* Bv = BT + (wPerView ? (size_t)v * Nc * K : 0) + (size_t)(bn * 256) * K;

  f32x4 acc[8][4];
#pragma unroll
  for (int m = 0; m < 8; m++)
#pragma unroll
    for (int n = 0; n < 4; n++) acc[m][n] = (f32x4){0.f, 0.f, 0.f, 0.f};

  const int wr = (w >> 2) * 128, wc = (w & 3) * 64;
  const int gq = lane >> 4, l15 = lane & 15;

#define STAGE_UNIT(Gp, LOFF, KH, KT)                                          \
  {                                                                           \
    _Pragma("unroll")                                                         \
    for (int g2 = 0; g2 < 2; g2++) {                                          \
      int u = g2 * 512 + tid;                                                 \
      int row_ = ((u >> 5) << 3) | (u & 7);                                   \
      int kkgl_ = (u >> 3) & 3;                                               \
      glds16(Gp + (size_t)row_ * K + (KT) * 64 + (KH) * 32 + kkgl_ * 8,       \
             ldsv + (LOFF) + (KH) * 8192 + u * 8);                            \
    }                                                                         \
  }

#define PH_READS(KK, MH, LOADB)                                               \
  {                                                                           \
    _Pragma("unroll")                                                         \
    for (int m = 0; m < 4; m++) {                                             \
      int ra = wr + (MH) * 64 + m * 16 + l15;                                 \
      aF[m] = *(const bf16x8*)&Ab[(KK) * 8192 + (ra >> 3) * 256 + gq * 64 +   \
                                  (ra & 7) * 8];                              \
    }                                                                         \
    if (LOADB) {                                                              \
      _Pragma("unroll")                                                       \
      for (int n = 0; n < 4; n++) {                                           \
        int rb = wc + n * 16 + l15;                                           \
        bF[n] = *(const bf16x8*)&Bb[(KK) * 8192 + (rb >> 3) * 256 + gq * 64 + \
                                    (rb & 7) * 8];                            \
      }                                                                       \
    }                                                                         \
  }

#define PH_MFMA(MH)                                                           \
  {                                                                           \
    __builtin_amdgcn_s_barrier();                                             \
    asm volatile("s_waitcnt lgkmcnt(0)" ::: "memory");                        \
    __builtin_amdgcn_sched_barrier(0);                                        \
    __builtin_amdgcn_s_setprio(1);                                            \
    _Pragma("unroll")                                                         \
    for (int m = 0; m < 4; m++)                                               \
      _Pragma("unroll")                                                       \
      for (int n = 0; n < 4; n++)                                             \
        acc[(MH) * 4 + m][n] = __builtin_amdgcn_mfma_f32_16x16x32_bf16(       \
            aF[m], bF[n], acc[(MH) * 4 + m][n], 0, 0, 0);                     \
    __builtin_amdgcn_s_setprio(0);                                            \
    __builtin_amdgcn_s_barrier();                                             \
  }

  const int nt = K >> 6;
  const int ni = nt >> 1;

  STAGE_UNIT(Av, 0,     0, 0);
  STAGE_UNIT(Bv, 16384, 0, 0);
  STAGE_UNIT(Av, 0,     1, 0);
  STAGE_UNIT(Bv, 16384, 1, 0);
  STAGE_UNIT(Av, 32768, 0, 1);
  STAGE_UNIT(Bv, 49152, 0, 1);
  asm volatile("s_waitcnt vmcnt(4)" ::: "memory");
  __builtin_amdgcn_s_barrier();

  bf16x8 aF[4], bF[4];
  for (int i = 0; i < ni; ++i) {
    int t1 = 2 * i + 1, t2 = 2 * i + 2, t3 = 2 * i + 3;
    bool more = (i + 1 < ni);
    const __bf16* Ab = ldsv;
    const __bf16* Bb = ldsv + 16384;
    PH_READS(0, 0, true);
    STAGE_UNIT(Av, 32768, 1, t1);
    asm volatile("s_waitcnt vmcnt(6)" ::: "memory");
    PH_MFMA(0);
    PH_READS(0, 1, false); STAGE_UNIT(Bv, 49152, 1, t1);              PH_MFMA(1);
    PH_READS(1, 0, true);
    if (more) {
      STAGE_UNIT(Av, 0, 0, t2);
      asm volatile("s_waitcnt vmcnt(6)" ::: "memory");
    } else {
      asm volatile("s_waitcnt vmcnt(4)" ::: "memory");
    }
    PH_MFMA(0);
    PH_READS(1, 1, false); if (more) STAGE_UNIT(Bv, 16384, 0, t2);    PH_MFMA(1);
    Ab = ldsv + 32768; Bb = ldsv + 49152;
    PH_READS(0, 0, true);
    if (more) {
      STAGE_UNIT(Av, 0, 1, t2);
      asm volatile("s_waitcnt vmcnt(6)" ::: "memory");
    } else {
      asm volatile("s_waitcnt vmcnt(0)" ::: "memory");
    }
    PH_MFMA(0);
    PH_READS(0, 1, false); if (more) STAGE_UNIT(Bv, 16384, 1, t2);    PH_MFMA(1);
    PH_READS(1, 0, true);
    if (more) {
      STAGE_UNIT(Av, 32768, 0, t3);
      asm volatile("s_waitcnt vmcnt(6)" ::: "memory");
    }
    PH_MFMA(0);
    PH_READS(1, 1, false);
    if (more) STAGE_UNIT(Bv, 49152, 0, t3);
    PH_MFMA(1);
  }

#undef STAGE_UNIT
#undef PH_READS
#undef PH_MFMA

  __bf16* Cv = C + (size_t)v * NN * Nc;
#pragma unroll
  for (int m = 0; m < 8; m++) {
    int rbase = bm * 256 + wr + m * 16 + (lane >> 4) * 4;
#pragma unroll
    for (int q = 0; q < 4; q++) {
      __bf16* cp = Cv + (size_t)(rbase + q) * Nc + bn * 256 + wc + l15;
#pragma unroll
      for (int n = 0; n < 4; n++) cp[n * 16] = (__bf16)acc[m][n][q];
    }
  }
}

__global__ __launch_bounds__(512, 2) void k_g256s(
    const __bf16* __restrict__ A, const __bf16* __restrict__ BT,
    __bf16* __restrict__ C, int K, int Nc, int nbn, int bpv, int wPerView)
{
  __shared__ __bf16 ldsv[65536];
  g256_body(A, BT, C, K, Nc, nbn, bpv, wPerView, blockIdx.x, gridDim.x, ldsv);
}

// paired GEMM launch: blocks [0,S1) = set 1, [S1,grid) = set 2
__global__ __launch_bounds__(512, 2) void k_g256p(
    const __bf16* A1, const __bf16* B1, __bf16* C1,
    int K1, int Nc1, int nbn1, int bpv1, int w1, int S1,
    const __bf16* A2, const __bf16* B2, __bf16* C2,
    int K2, int Nc2, int nbn2, int bpv2, int w2)
{
  __shared__ __bf16 ldsv[65536];
  if ((int)blockIdx.x < S1)
    g256_body(A1, B1, C1, K1, Nc1, nbn1, bpv1, w1, blockIdx.x, S1, ldsv);
  else
    g256_body(A2, B2, C2, K2, Nc2, nbn2, bpv2, w2, blockIdx.x - S1,
              gridDim.x - S1, ldsv);
}

// ---------------------------------------------------------------------------
// CSR SpMM v4 (final): R11 geometry (4 rows/block, 256 thr, occupancy ~79%)
// + R12 GACC (int32 offsets, dword bf16 unpack — fewer VALU ops, identical
// memory pattern and bit-identical sums).
// ---------------------------------------------------------------------------
template <int LDIN, int FOFF, int F, int CHUNKS, int MODE>
__device__ __forceinline__ void spmm_body(
    int id, const __bf16* __restrict__ in, const int* __restrict__ rp,
    const int2* __restrict__ sedge, void* __restrict__ out,
    const __bf16* __restrict__ h1, const __bf16* __restrict__ h2)
{
  int s = id & 7, j = id >> 3;
  int ch, v, rowblk;
  if (CHUNKS == 2) {                 // XCDs 0-3 -> chunk0, 4-7 -> chunk1
    ch = s >> 2; int q = s & 3;
    v = j / 400; int t = j - v * 400;
    rowblk = t * 4 + q;              // [0,1600)
  } else {
    ch = 0;
    v = j / 200; int t = j - v * 200;
    rowblk = t * 8 + s;              // [0,1600)
  }
  int wid = threadIdx.x >> 6, lane = threadIdx.x & 63;
  int n = rowblk * 4 + wid;
  int f0 = ch * 256 + lane * 4;

  const int* rpv = rp + v * (NN + 1);
  int e = rpv[n], end = rpv[n + 1];
  const int2* ev = sedge + (size_t)v * EE;
  const __bf16* inv = in + (size_t)v * NN * LDIN + FOFF;   // wave-uniform base

  float a0 = 0.f, a1 = 0.f, a2 = 0.f, a3 = 0.f;

#define GACC(EP)                                                              \
  {                                                                           \
    float wv = __int_as_float((EP).y);                                        \
    int off = (EP).x * LDIN + f0;                                             \
    uint2 rdw = *(const uint2*)(inv + off);                                   \
    a0 += wv * __uint_as_float(rdw.x << 16);                                  \
    a1 += wv * __uint_as_float(rdw.x & 0xffff0000u);                          \
    a2 += wv * __uint_as_float(rdw.y << 16);                                  \
    a3 += wv * __uint_as_float(rdw.y & 0xffff0000u);                          \
  }

  for (; e + 8 <= end; e += 8) {
    int2 ee[8];
#pragma unroll
    for (int u = 0; u < 8; u++) ee[u] = ev[e + u];
#pragma unroll
    for (int u = 0; u < 8; u++) GACC(ee[u]);
  }
  if (e + 4 <= end) {
    int2 ee[4];
#pragma unroll
    for (int u = 0; u < 4; u++) ee[u] = ev[e + u];
#pragma unroll
    for (int u = 0; u < 4; u++) GACC(ee[u]);
    e += 4;
  }
  for (; e < end; ++e) {
    int2 e0 = ev[e];
    GACC(e0);
  }
#undef GACC

  if (MODE == 0) {
    __bf16* o = (__bf16*)out + ((size_t)v * NN + n) * F + f0;
    bf16x4 ov;
    ov[0] = (__bf16)fmaxf(a0, 0.f); ov[1] = (__bf16)fmaxf(a1, 0.f);
    ov[2] = (__bf16)fmaxf(a2, 0.f); ov[3] = (__bf16)fmaxf(a3, 0.f);
    *(bf16x4*)o = ov;
  } else if (MODE == 1) {
    float* o = (float*)out + ((size_t)v * NN + n) * ZF + f0;
    o[0] = fmaxf(a0, 0.f); o[1] = fmaxf(a1, 0.f);
    o[2] = fmaxf(a2, 0.f); o[3] = fmaxf(a3, 0.f);
  } else {
    const __bf16* hh = h1 + ((size_t)v * NN + n) * 512 + f0;
    const __bf16* mm = h2 + ((size_t)v * NN + n) * 512 + f0;
    ushort4 hu = *(const ushort4*)hh;
    ushort4 mu = *(const ushort4*)mm;
    float* o = (float*)out + ((size_t)v * NN + n) * ZF + CC + f0;
    o[0] = (b2f(hu.x) + b2f(mu.x) + a0) * (1.f / 3.f);
    o[1] = (b2f(hu.y) + b2f(mu.y) + a1) * (1.f / 3.f);
    o[2] = (b2f(hu.z) + b2f(mu.z) + a2) * (1.f / 3.f);
    o[3] = (b2f(hu.w) + b2f(mu.w) + a3) * (1.f / 3.f);
  }
}

// paired spmm launch: [0,S1) = variant 1, [S1,grid) = variant 2.
// S1 = 19200 is 0 mod 8 -> XCD phase of segment 2 preserved.
template <int S1,
          int LD1, int FO1, int F1, int CH1, int MO1,
          int LD2, int FO2, int F2, int CH2, int MO2>
__global__ __launch_bounds__(256) void k_spmm2(
    const __bf16* __restrict__ in1, void* __restrict__ out1,
    const __bf16* __restrict__ in2, void* __restrict__ out2,
    const int* __restrict__ rp, const int2* __restrict__ sedge,
    const __bf16* __restrict__ h1, const __bf16* __restrict__ h2)
{
  int id = blockIdx.x;
  if (id < S1) spmm_body<LD1, FO1, F1, CH1, MO1>(id, in1, rp, sedge, out1, h1, h2);
  else         spmm_body<LD2, FO2, F2, CH2, MO2>(id - S1, in2, rp, sedge, out2, h1, h2);
}

// ---------------------------------------------------------------------------
// Gate
// ---------------------------------------------------------------------------
__global__ __launch_bounds__(256) void k_gate(
    const float* __restrict__ Z, const float* __restrict__ gw,
    const float* __restrict__ gb, float* __restrict__ zg)
{
  __shared__ float Zl[NVIEW * ZF];
  __shared__ float sred[36];
  __shared__ float pl[36];
  int n = blockIdx.x, tid = threadIdx.x;

  for (int idx = tid; idx < NVIEW * ZF; idx += 256) {
    int i = idx / ZF, f = idx - i * ZF;
    Zl[idx] = Z[((size_t)i * NN + n) * ZF + f];
  }
  if (tid < 36) sred[tid] = 0.f;
  __syncthreads();

  float acc[36];
#pragma unroll
  for (int p = 0; p < 36; p++) acc[p] = 0.f;
#pragma unroll
  for (int q = 0; q < 3; q++) {
    int f = tid + q * 256;
    float zv[NVIEW];
#pragma unroll
    for (int i = 0; i < NVIEW; i++) zv[i] = Zl[i * ZF + f];
#pragma unroll
    for (int k = 0; k < NVIEW; k++)
#pragma unroll
      for (int i = 0; i < NVIEW; i++)
        acc[k * 6 + i] += zv[i] * gw[(k * 6 + i) * ZF + f];
  }
  int lane = tid & 63;
#pragma unroll
  for (int p = 0; p < 36; p++) {
    float x = acc[p];
    x += __shfl_down(x, 32, 64);
    x += __shfl_down(x, 16, 64);
    x += __shfl_down(x, 8, 64);
    x += __shfl_down(x, 4, 64);
    x += __shfl_down(x, 2, 64);
    x += __shfl_down(x, 1, 64);
    if (lane == 0) atomicAdd(&sred[p], x);
  }
  __syncthreads();

  if (tid < NVIEW) {
    int k = tid;
    float sc[NVIEW];
    float mx = -1e30f;
#pragma unroll
    for (int i = 0; i < NVIEW; i++) {
      sc[i] = sred[k * 6 + i] + gb[k * 6 + i];
      mx = fmaxf(mx, sc[i]);
    }
    float sum = 0.f;
#pragma unroll
    for (int i = 0; i < NVIEW; i++) { sc[i] = __expf(sc[i] - mx); sum += sc[i]; }
    float inv = 1.f / sum;
#pragma unroll
    for (int i = 0; i < NVIEW; i++) pl[k * 6 + i] = sc[i] * inv;
  }
  __syncthreads();

#pragma unroll
  for (int q = 0; q < 3; q++) {
    int f = tid + q * 256;
    float zv[NVIEW];
#pragma unroll
    for (int i = 0; i < NVIEW; i++) zv[i] = Zl[i * ZF + f];
#pragma unroll
    for (int k = 0; k < NVIEW; k++) {
      float o = 0.f;
#pragma unroll
      for (int i = 0; i < NVIEW; i++) o += pl[k * 6 + i] * zv[i];
      zg[((size_t)k * NN + n) * ZF + f] = o;
    }
  }
}

// ---------------------------------------------------------------------------
extern "C" void kernel_launch(void* const* d_in, const int* in_sizes, int n_in,
                              void* d_out, int out_size, void* d_ws, size_t ws_size,
                              hipStream_t stream) {
  const float* x    = (const float*)d_in[0];
  const float* aval = (const float*)d_in[1];
  const float* Wb   = (const float*)d_in[2];
  const float* Wo   = (const float*)d_in[3];
  const float* Wf   = (const float*)d_in[4];
  const float* Wc0  = (const float*)d_in[5];
  const float* Wc1  = (const float*)d_in[6];
  const float* Wc2  = (const float*)d_in[7];
  const float* gw   = (const float*)d_in[8];
  const float* gb   = (const float*)d_in[9];
  const int*   asrc = (const int*)d_in[10];
  const int*   adst = (const int*)d_in[11];

  float* zg = (float*)d_out;                       // [6][6400][768]
  float* Z  = zg + (size_t)NVIEW * NN * ZF;        // [6][6400][768]
  // xb (79 MB bf16 copy of x) is stashed at the head of d_out: its last read
  // (the fused GEMM) precedes the first write to Z (spmm modes 1/2) in stream
  // order; zg is written only by the final gate kernel.
  __bf16* xb = (__bf16*)d_out;

  char* w = (char*)d_ws;
  auto alloc = [&](size_t bytes) {
    char* p = w;
    w += (bytes + 255) & ~(size_t)255;
    return p;
  };
  int*    hist  = (int*)alloc((size_t)NVIEW * NN * 4);          // reused as cursor
  int*    rp    = (int*)alloc((size_t)NVIEW * (NN + 1) * 4);
  int2*   sedge = (int2*)alloc((size_t)NVIEW * EE * 8);
  __bf16* Wfu   = (__bf16*)alloc((size_t)NVIEW * ZF * DD * 2);  // [v][768][2048]
  __bf16* WoT   = (__bf16*)alloc((size_t)NVIEW * HH * HH * 2);
  __bf16* WfT   = (__bf16*)alloc((size_t)NVIEW * HH * HH * 2);
  __bf16* Wc1T  = (__bf16*)alloc((size_t)CC * CC * 2);
  __bf16* Wc2T  = (__bf16*)alloc((size_t)CC * CC * 2);
  __bf16* tf768 = (__bf16*)alloc((size_t)NVIEW * NN * ZF * 2);  // fused GEMM out
  __bf16* t512b = (__bf16*)alloc((size_t)NVIEW * NN * HH * 2);
  __bf16* hidb  = (__bf16*)alloc((size_t)NVIEW * NN * HH * 2);
  __bf16* midb  = (__bf16*)alloc((size_t)NVIEW * NN * HH * 2);
  __bf16* tcb   = (__bf16*)alloc((size_t)NVIEW * NN * CC * 2);
  __bf16* cbb   = (__bf16*)alloc((size_t)NVIEW * NN * CC * 2);

  // ---- CSR build + precision/layout prep (merged) ----
  (void)hipMemsetAsync(hist, 0, (size_t)NVIEW * NN * 4, stream);
  k_prep<<<94016, 256, 0, stream>>>(adst, hist, x, xb, Wb, Wc0, Wfu,
                                    Wo, Wf, WoT, WfT, Wc1, Wc2, Wc1T, Wc2T);
  k_scan<<<NVIEW, 1024, 0, stream>>>(hist, rp, hist);   // cursor fused (alias)
  k_scatter<<<dim3(800, NVIEW), 256, 0, stream>>>(asrc, adst, aval, hist, sedge);

  // ---- fused first-layer GEMM: [6400,2048] @ [2048,768] per view ----
  k_g256s<<<450, 512, 0, stream>>>(xb, Wfu, tf768, DD, ZF, 3, 75, 1);

  // ---- layer pipeline: view path (512f) + common path (256f), paired ----
  k_spmm2<19200, 768, 0, 512, 2, 0, 768, 512, 256, 1, 0>
      <<<28800, 256, 0, stream>>>(tf768, hidb, tf768, cbb, rp, sedge, nullptr, nullptr);
  k_g256p<<<450, 512, 0, stream>>>(hidb, WoT, t512b, HH, HH, 2, 50, 1, 300,
                                   cbb, Wc1T, tcb, CC, CC, 1, 25, 0);
  k_spmm2<19200, 512, 0, 512, 2, 0, 256, 0, 256, 1, 0>
      <<<28800, 256, 0, stream>>>(t512b, midb, tcb, cbb, rp, sedge, nullptr, nullptr);
  k_g256p<<<450, 512, 0, stream>>>(midb, WfT, t512b, HH, HH, 2, 50, 1, 300,
                                   cbb, Wc2T, tcb, CC, CC, 1, 25, 0);
  k_spmm2<19200, 512, 0, 512, 2, 2, 256, 0, 256, 1, 1>
      <<<28800, 256, 0, stream>>>(t512b, Z, tcb, Z, rp, sedge, hidb, midb);

  // ---- gated fusion ----
  k_gate<<<NN, 256, 0, stream>>>(Z, gw, gb, zg);
}